// Round 3
// baseline (1059.338 us; speedup 1.0000x reference)
//
#include <hip/hip_runtime.h>
#include <math.h>

// Problem constants (z: [16,4096,128] f32, emb_w: [1024,128] f32, unit rows)
#define D       128
#define NE      1024
#define NROWS   65536   // B*N
#define NB      16

// ---- output float offsets (total 16,924,675 floats) ----
#define OUT_ZQ    0            // [16,4096,128]
#define OUT_LOSS  8388608      // scalar
#define OUT_SAMP  8388609      // [16,1024]
#define OUT_IDX   8404993      // [16,4096] (float)
#define OUT_VAR   8470529      // scalar
#define OUT_DIST  8470530      // scalar
#define OUT_SI    8470531      // [16,4096] (float)
#define OUT_ZN    8536067      // [16,4096,128]  (NOT 16B-aligned -> scalar stores)

// ---- workspace float offsets (total 137,728 floats = 538 KB) ----
#define WS_IDX    0            // int[65536]
#define WS_WW     65536        // float[1024]
#define WS_FLAGS  66560        // int[1024]
#define WS_MIN2   67584        // float[1024]
#define WS_VAR    68608        // float[1024]
#define WS_LOSSP  69632        // float[512]
#define WS_COLSQP 70144        // float[512*128]
#define WS_COLSQ  135680       // float[16*128]

// numpy pairwise sum of squares over 128 contiguous floats.
__device__ __forceinline__ float npsq_sum128(const float* p) {
  float a[8];
#pragma unroll
  for (int m = 0; m < 8; ++m) a[m] = __fmul_rn(p[m], p[m]);
  for (int k = 8; k < 128; k += 8) {
#pragma unroll
    for (int m = 0; m < 8; ++m) a[m] = __fadd_rn(a[m], __fmul_rn(p[k + m], p[k + m]));
  }
  float s01 = __fadd_rn(a[0], a[1]);
  float s23 = __fadd_rn(a[2], a[3]);
  float s45 = __fadd_rn(a[4], a[5]);
  float s67 = __fadd_rn(a[6], a[7]);
  return __fadd_rn(__fadd_rn(s01, s23), __fadd_rn(s45, s67));
}

// ---- ww[c] = sum(w[c]^2), numpy order ----
__global__ __launch_bounds__(128) void k_ww(const float* __restrict__ w,
                                            float* __restrict__ ws) {
  int c = blockIdx.x * 128 + threadIdx.x;
  if (c >= NE) return;
  ws[WS_WW + c] = npsq_sum128(w + c * D);
}

// ---- codebook self-distance stats: per row i, second-min and unbiased var ----
__global__ __launch_bounds__(128) void k_cb(const float* __restrict__ w,
                                            float* __restrict__ ws) {
  const int i = blockIdx.x;
  const int t = threadIdx.x;
  __shared__ float4 wi[32];
  __shared__ float r1[128], r2[128], rs[128], rq[128];
  if (t < 32) wi[t] = ((const float4*)(w + i * D))[t];
  __syncthreads();
  const float wwi = ws[WS_WW + i];
  float m1 = INFINITY, m2 = INFINITY, sum = 0.f, sq = 0.f;
  for (int jj = 0; jj < 8; ++jj) {
    int j = t + jj * 128;
    const float4* pj = (const float4*)(w + j * D);
    float acc = 0.f;
#pragma unroll
    for (int k4 = 0; k4 < 32; ++k4) {
      float4 a = wi[k4], b = pj[k4];
      acc = fmaf(a.x, b.x, acc); acc = fmaf(a.y, b.y, acc);
      acc = fmaf(a.z, b.z, acc); acc = fmaf(a.w, b.w, acc);
    }
    float t1 = __fadd_rn(wwi, ws[WS_WW + j]);
    float d  = __fsub_rn(t1, __fmul_rn(2.f, acc));
    sum += d; sq = fmaf(d, d, sq);
    if (d < m1) { m2 = m1; m1 = d; } else if (d < m2) m2 = d;
  }
  r1[t] = m1; r2[t] = m2; rs[t] = sum; rq[t] = sq;
  __syncthreads();
  for (int s = 64; s > 0; s >>= 1) {
    if (t < s) {
      float a1 = r1[t], a2 = r2[t], b1 = r1[t + s], b2 = r2[t + s];
      r1[t] = fminf(a1, b1);
      r2[t] = fminf(fmaxf(a1, b1), fminf(a2, b2));
      rs[t] += rs[t + s]; rq[t] += rq[t + s];
    }
    __syncthreads();
  }
  if (t == 0) {
    ws[WS_MIN2 + i] = r2[0];
    float S = rs[0], Q = rq[0];
    ws[WS_VAR + i] = (Q - S * S / (float)NE) / (float)(NE - 1);
  }
}

// =====================================================================
// k_quant v3: lane <-> z-row. z row in 4x f32x32 ext-vectors (constant
// subscripts only -> guaranteed VGPRs). w streamed as uniform-address
// global_load_dwordx4 (all lanes same addr -> one line + broadcast; no
// VALU cost, no LDS). Code-pair (2 indep fma chains) with chunk-level
// A/B double buffer; compiler schedules vmcnt. Waves {0,1}: rows,
// codes 0..511; waves {2,3}: same rows, codes 512..1023; LDS combine.
// Numerics bit-identical to R1/R2 (sequential-k fmaf, numpy zz).
// =====================================================================
typedef __attribute__((ext_vector_type(32))) float f32x32;

#define ZF(k) ((k) < 32 ? zA[(k) & 31] : ((k) < 64 ? zB[(k) & 31] \
             : ((k) < 96 ? zC[(k) & 31] : zD[(k) & 31])))

#define LOADP(P0,P1,P2,P3,Q0,Q1,Q2,Q3, PTR, OFF) do {            \
    const float4* _p = (const float4*)((PTR) + (OFF));           \
    const float4* _q = (const float4*)((PTR) + D + (OFF));       \
    P0 = _p[0]; P1 = _p[1]; P2 = _p[2]; P3 = _p[3];              \
    Q0 = _q[0]; Q1 = _q[1]; Q2 = _q[2]; Q3 = _q[3];              \
  } while (0)

#define C4(V, W, KK)                                              \
  acc0 = fmaf(ZF((KK)+0), (V).x, acc0); acc1 = fmaf(ZF((KK)+0), (W).x, acc1); \
  acc0 = fmaf(ZF((KK)+1), (V).y, acc0); acc1 = fmaf(ZF((KK)+1), (W).y, acc1); \
  acc0 = fmaf(ZF((KK)+2), (V).z, acc0); acc1 = fmaf(ZF((KK)+2), (W).z, acc1); \
  acc0 = fmaf(ZF((KK)+3), (V).w, acc0); acc1 = fmaf(ZF((KK)+3), (W).w, acc1);

#define CONS(P0,P1,P2,P3,Q0,Q1,Q2,Q3, K0) do {                    \
    C4(P0, Q0, (K0)+0)  C4(P1, Q1, (K0)+4)                        \
    C4(P2, Q2, (K0)+8)  C4(P3, Q3, (K0)+12)                       \
  } while (0)

__global__ __launch_bounds__(256, 2) void k_quant(const float* __restrict__ z,
                                                  const float* __restrict__ wsrc,
                                                  float* __restrict__ wsf,
                                                  float* __restrict__ out) {
  const int t = threadIdx.x;
  const int lane = t & 63;
  const int wrow = (t >> 6) & 1;             // row-group within block
  const int chalf = t >> 7;                  // code half (wave-uniform)
  const int lr = wrow * 64 + lane;           // 0..127 row within block
  const int gr = blockIdx.x * 128 + lr;      // global row

  // ---- z row into ext-vector registers (constant indices only) ----
  f32x32 zA, zB, zC, zD;
  {
    const float4* zp = (const float4*)(z + (size_t)gr * D);
#pragma unroll
    for (int k4 = 0; k4 < 8; ++k4) {
      float4 v = zp[k4];
      zA[4*k4+0] = v.x; zA[4*k4+1] = v.y; zA[4*k4+2] = v.z; zA[4*k4+3] = v.w;
    }
#pragma unroll
    for (int k4 = 0; k4 < 8; ++k4) {
      float4 v = zp[8 + k4];
      zB[4*k4+0] = v.x; zB[4*k4+1] = v.y; zB[4*k4+2] = v.z; zB[4*k4+3] = v.w;
    }
#pragma unroll
    for (int k4 = 0; k4 < 8; ++k4) {
      float4 v = zp[16 + k4];
      zC[4*k4+0] = v.x; zC[4*k4+1] = v.y; zC[4*k4+2] = v.z; zC[4*k4+3] = v.w;
    }
#pragma unroll
    for (int k4 = 0; k4 < 8; ++k4) {
      float4 v = zp[24 + k4];
      zD[4*k4+0] = v.x; zD[4*k4+1] = v.y; zD[4*k4+2] = v.z; zD[4*k4+3] = v.w;
    }
  }

  // ---- zz, exact numpy pairwise order ----
  float zz;
  {
    float a[8];
#pragma unroll
    for (int m = 0; m < 8; ++m) a[m] = __fmul_rn(ZF(m), ZF(m));
#pragma unroll
    for (int k = 8; k < 128; k += 8)
#pragma unroll
      for (int m = 0; m < 8; ++m)
        a[m] = __fadd_rn(a[m], __fmul_rn(ZF(k + m), ZF(k + m)));
    float s01 = __fadd_rn(a[0], a[1]), s23 = __fadd_rn(a[2], a[3]);
    float s45 = __fadd_rn(a[4], a[5]), s67 = __fadd_rn(a[6], a[7]);
    zz = __fadd_rn(__fadd_rn(s01, s23), __fadd_rn(s45, s67));
  }

  float best = INFINITY; int bidx = 0;
  const float* wbase = wsrc + (size_t)chalf * 512 * D;
  const float* cw = wbase;

  float4 A00, A01, A02, A03, A10, A11, A12, A13;   // buffer A (2 codes x 16 k)
  float4 B00, B01, B02, B03, B10, B11, B12, B13;   // buffer B

  LOADP(A00,A01,A02,A03,A10,A11,A12,A13, cw, 0);   // prologue

  for (int cp = 0; cp < 256; ++cp) {
    const int c0 = chalf * 512 + cp * 2;
    const float2 wwp = *(const float2*)&wsf[WS_WW + c0];
    const float* nw = (cp == 255) ? wbase : (cw + 2 * D);  // wrap-safe phantom
    float acc0 = 0.f, acc1 = 0.f;

    LOADP(B00,B01,B02,B03,B10,B11,B12,B13, cw, 16);
    CONS (A00,A01,A02,A03,A10,A11,A12,A13, 0);
    LOADP(A00,A01,A02,A03,A10,A11,A12,A13, cw, 32);
    CONS (B00,B01,B02,B03,B10,B11,B12,B13, 16);
    LOADP(B00,B01,B02,B03,B10,B11,B12,B13, cw, 48);
    CONS (A00,A01,A02,A03,A10,A11,A12,A13, 32);
    LOADP(A00,A01,A02,A03,A10,A11,A12,A13, cw, 64);
    CONS (B00,B01,B02,B03,B10,B11,B12,B13, 48);
    LOADP(B00,B01,B02,B03,B10,B11,B12,B13, cw, 80);
    CONS (A00,A01,A02,A03,A10,A11,A12,A13, 64);
    LOADP(A00,A01,A02,A03,A10,A11,A12,A13, cw, 96);
    CONS (B00,B01,B02,B03,B10,B11,B12,B13, 80);
    LOADP(B00,B01,B02,B03,B10,B11,B12,B13, cw, 112);
    CONS (A00,A01,A02,A03,A10,A11,A12,A13, 96);
    LOADP(A00,A01,A02,A03,A10,A11,A12,A13, nw, 0);
    CONS (B00,B01,B02,B03,B10,B11,B12,B13, 112);

    float d0 = __fsub_rn(__fadd_rn(zz, wwp.x), __fmul_rn(2.f, acc0));
    if (d0 < best) { best = d0; bidx = c0; }
    float d1 = __fsub_rn(__fadd_rn(zz, wwp.y), __fmul_rn(2.f, acc1));
    if (d1 < best) { best = d1; bidx = c0 + 1; }
    cw = nw;
  }

  // ---- combine the two code-halves per row (half-0 wins ties) ----
  __shared__ float sv[128];
  __shared__ int   sidx[128];
  if (chalf == 0) { sv[lr] = best; sidx[lr] = bidx; }
  __syncthreads();
  if (chalf == 1) {
    float v1 = sv[lr]; int i1 = sidx[lr];
    int mi = (best < v1) ? bidx : i1;
    ((int*)wsf)[WS_IDX + gr] = mi;
    out[OUT_IDX + gr] = (float)mi;
    out[OUT_SI  + gr] = (float)mi;
    ((int*)wsf)[WS_FLAGS + mi] = 1;   // benign race: all writers store 1
  }
}

// ---- gather z_q -> out0, loss partials, per-column square partials ----
__global__ __launch_bounds__(256) void k_gather(const float* __restrict__ z,
                                                const float* __restrict__ w,
                                                float* __restrict__ ws,
                                                float* __restrict__ out) {
  __shared__ float csp[32][8][4];
  __shared__ float lred[256];
  const int t = threadIdx.x, blk = blockIdx.x;
  const int c4 = t & 31, rg = t >> 5;
  float lp = 0.f;
  float csx = 0.f, csy = 0.f, csz = 0.f, csw = 0.f;
  for (int m = 0; m < 16; ++m) {
    int r  = rg + 8 * m;
    int gr = blk * 128 + r;
    int idx = ((const int*)ws)[WS_IDX + gr];
    float4 q  = *(const float4*)&w[idx * D + c4 * 4];
    float4 zv = *(const float4*)&z[(size_t)gr * D + c4 * 4];
    *(float4*)&out[OUT_ZQ + (size_t)gr * D + c4 * 4] = q;
    float dx = q.x - zv.x, dy = q.y - zv.y, dz = q.z - zv.z, dw = q.w - zv.w;
    lp = fmaf(dx, dx, lp); lp = fmaf(dy, dy, lp);
    lp = fmaf(dz, dz, lp); lp = fmaf(dw, dw, lp);
    csx = fmaf(q.x, q.x, csx); csy = fmaf(q.y, q.y, csy);
    csz = fmaf(q.z, q.z, csz); csw = fmaf(q.w, q.w, csw);
  }
  csp[c4][rg][0] = csx; csp[c4][rg][1] = csy;
  csp[c4][rg][2] = csz; csp[c4][rg][3] = csw;
  lred[t] = lp;
  __syncthreads();
  for (int s = 128; s > 0; s >>= 1) {
    if (t < s) lred[t] += lred[t + s];
    __syncthreads();
  }
  if (t == 0) ws[WS_LOSSP + blk] = lred[0];
  if (t < 128) {
    int dcol = t;
    float s = 0.f;
    for (int g = 0; g < 8; ++g) s += csp[dcol >> 2][g][dcol & 3];
    ws[WS_COLSQP + blk * 128 + dcol] = s;
  }
}

// ---- combine colsq partials (deterministic fixed order) ----
__global__ __launch_bounds__(256) void k_colsq_final(float* __restrict__ ws) {
  int t = blockIdx.x * 256 + threadIdx.x;
  if (t >= NB * D) return;
  int b = t >> 7, dcol = t & 127;
  float s = 0.f;
  for (int rb = 0; rb < 32; ++rb)
    s += ws[WS_COLSQP + (b * 32 + rb) * 128 + dcol];
  ws[WS_COLSQ + t] = s;
}

// ---- zn = z_q / max(||z_q[b,:,d]||, 1e-12)  (normalize over N axis) ----
__global__ __launch_bounds__(256) void k_zn(const float* __restrict__ ws,
                                            float* __restrict__ out) {
  int u = blockIdx.x * 256 + threadIdx.x;
  const int total4 = NROWS * D / 4;
  for (; u < total4; u += gridDim.x * 256) {
    float4 q = ((const float4*)out)[u];
    int o = u * 4;
    int b = o >> 19;
    int dcol = o & 127;
    float4 cs = *(const float4*)&ws[WS_COLSQ + b * 128 + dcol];
    out[OUT_ZN + o + 0] = q.x / fmaxf(sqrtf(cs.x), 1e-12f);
    out[OUT_ZN + o + 1] = q.y / fmaxf(sqrtf(cs.y), 1e-12f);
    out[OUT_ZN + o + 2] = q.z / fmaxf(sqrtf(cs.z), 1e-12f);
    out[OUT_ZN + o + 3] = q.w / fmaxf(sqrtf(cs.w), 1e-12f);
  }
}

// ---- finalize scalars + sampled_idx ----
__global__ __launch_bounds__(1024) void k_final(float* __restrict__ ws,
                                                float* __restrict__ out) {
  __shared__ float s1[1024], s2[1024], s3[1024];
  int t = threadIdx.x;
  s1[t] = (t < 512) ? ws[WS_LOSSP + t] : 0.f;
  s2[t] = ws[WS_MIN2 + t];
  s3[t] = ws[WS_VAR + t];
  __syncthreads();
  for (int s = 512; s > 0; s >>= 1) {
    if (t < s) { s1[t] += s1[t + s]; s2[t] += s2[t + s]; s3[t] += s3[t + s]; }
    __syncthreads();
  }
  if (t == 0) {
    float m = s1[0] / 8388608.f;
    out[OUT_LOSS] = m + 0.9f * m;
    out[OUT_VAR]  = s3[0] / 1024.f;
    out[OUT_DIST] = s2[0] / 1024.f;
  }
  const int* flags = (const int*)ws + WS_FLAGS;
  for (int i = t; i < NB * NE; i += 1024)
    out[OUT_SAMP + i] = (i < NE && flags[i] != 0) ? 1.f : 0.f;
}

extern "C" void kernel_launch(void* const* d_in, const int* in_sizes, int n_in,
                              void* d_out, int out_size, void* d_ws, size_t ws_size,
                              hipStream_t stream) {
  const float* z = (const float*)d_in[0];
  const float* w = (const float*)d_in[1];
  float* out = (float*)d_out;
  float* ws  = (float*)d_ws;

  hipMemsetAsync((char*)d_ws + (size_t)WS_FLAGS * 4, 0, NE * 4, stream);
  hipLaunchKernelGGL(k_ww,          dim3(8),    dim3(128),  0, stream, w, ws);
  hipLaunchKernelGGL(k_cb,          dim3(1024), dim3(128),  0, stream, w, ws);
  hipLaunchKernelGGL(k_quant,       dim3(512),  dim3(256),  0, stream, z, w, ws, out);
  hipLaunchKernelGGL(k_gather,      dim3(512),  dim3(256),  0, stream, z, w, ws, out);
  hipLaunchKernelGGL(k_colsq_final, dim3(8),    dim3(256),  0, stream, ws);
  hipLaunchKernelGGL(k_zn,          dim3(2048), dim3(256),  0, stream, ws, out);
  hipLaunchKernelGGL(k_final,       dim3(1),    dim3(1024), 0, stream, ws, out);
}

// Round 4
// 233.243 us; speedup vs baseline: 4.5418x; 4.5418x over previous
//
#include <hip/hip_runtime.h>
#include <math.h>

// Problem constants (z: [16,4096,128] f32, emb_w: [1024,128] f32, unit rows)
#define D       128
#define NE      1024
#define NROWS   65536   // B*N
#define NB      16

// ---- output float offsets (total 16,924,675 floats) ----
#define OUT_ZQ    0            // [16,4096,128]
#define OUT_LOSS  8388608      // scalar
#define OUT_SAMP  8388609      // [16,1024]
#define OUT_IDX   8404993      // [16,4096] (float)
#define OUT_VAR   8470529      // scalar
#define OUT_DIST  8470530      // scalar
#define OUT_SI    8470531      // [16,4096] (float)
#define OUT_ZN    8536067      // [16,4096,128]  (overwritten LAST by k_zn)

// Scratch inside the OUT_ZN region (k_zn overwrites it at the very end).
// SCR is 16B-aligned (8536068*4 % 16 == 0).
#define SCR       8536068      // wh: 131072 ushorts (256KB)
#define SCR_WL    (SCR + 65536)   // wl: 131072 ushorts
#define SCR_RF    (SCR + 131072)  // rflag: 65536 ints

// ---- workspace float offsets (538 KB total) ----
#define WS_IDX    0            // int[65536]
#define WS_WW     65536        // float[1024]
#define WS_FLAGS  66560        // int[1024]
#define WS_MIN2   67584        // float[1024]
#define WS_VAR    68608        // float[1024]
#define WS_LOSSP  69632        // float[512]
#define WS_COLSQP 70144        // float[512*128]
#define WS_COLSQ  135680       // float[16*128]

#define MARGIN 2e-3f

typedef __attribute__((ext_vector_type(8))) short s16x8;   // 8 bf16 (4 VGPR)
typedef __attribute__((ext_vector_type(4))) float f32x4;

__device__ __forceinline__ unsigned short f2bf(float f) {  // bf16 RNE
  unsigned int u = __float_as_uint(f);
  return (unsigned short)((u + 0x7FFFu + ((u >> 16) & 1u)) >> 16);
}
__device__ __forceinline__ float bf2f(unsigned short h) {
  return __uint_as_float(((unsigned int)h) << 16);
}

// numpy pairwise sum of squares over 128 contiguous floats (exact ref order).
__device__ __forceinline__ float npsq_sum128(const float* p) {
  float a[8];
#pragma unroll
  for (int m = 0; m < 8; ++m) a[m] = __fmul_rn(p[m], p[m]);
  for (int k = 8; k < 128; k += 8) {
#pragma unroll
    for (int m = 0; m < 8; ++m) a[m] = __fadd_rn(a[m], __fmul_rn(p[k + m], p[k + m]));
  }
  float s01 = __fadd_rn(a[0], a[1]);
  float s23 = __fadd_rn(a[2], a[3]);
  float s45 = __fadd_rn(a[4], a[5]);
  float s67 = __fadd_rn(a[6], a[7]);
  return __fadd_rn(__fadd_rn(s01, s23), __fadd_rn(s45, s67));
}

// ---- ww[c] = sum(w[c]^2), numpy order ----
__global__ __launch_bounds__(128) void k_ww(const float* __restrict__ w,
                                            float* __restrict__ ws) {
  int c = blockIdx.x * 128 + threadIdx.x;
  if (c >= NE) return;
  ws[WS_WW + c] = npsq_sum128(w + c * D);
}

// ---- split w into bf16 hi/lo, stored XOR-swizzled in the OUT scratch ----
// byte(c,k) = (c*256 + 2k) ^ ((c&7)<<4)  -> conflict-free ds_read_b128 frags
__global__ __launch_bounds__(128) void k_wsplit(const float* __restrict__ w,
                                                float* __restrict__ out) {
  int c = blockIdx.x, k = threadIdx.x;
  float f = w[c * D + k];
  unsigned short h = f2bf(f);
  unsigned short l = f2bf(f - bf2f(h));
  unsigned int by = (unsigned int)(c * 256 + 2 * k) ^ (unsigned int)((c & 7) << 4);
  ((unsigned short*)(out + SCR))[by >> 1]    = h;
  ((unsigned short*)(out + SCR_WL))[by >> 1] = l;
}

// ---- codebook self-distance stats ----
__global__ __launch_bounds__(128) void k_cb(const float* __restrict__ w,
                                            float* __restrict__ ws) {
  const int i = blockIdx.x;
  const int t = threadIdx.x;
  __shared__ float4 wi[32];
  __shared__ float r1[128], r2[128], rs[128], rq[128];
  if (t < 32) wi[t] = ((const float4*)(w + i * D))[t];
  __syncthreads();
  const float wwi = ws[WS_WW + i];
  float m1 = INFINITY, m2 = INFINITY, sum = 0.f, sq = 0.f;
  for (int jj = 0; jj < 8; ++jj) {
    int j = t + jj * 128;
    const float4* pj = (const float4*)(w + j * D);
    float acc = 0.f;
#pragma unroll
    for (int k4 = 0; k4 < 32; ++k4) {
      float4 a = wi[k4], b = pj[k4];
      acc = fmaf(a.x, b.x, acc); acc = fmaf(a.y, b.y, acc);
      acc = fmaf(a.z, b.z, acc); acc = fmaf(a.w, b.w, acc);
    }
    float t1 = __fadd_rn(wwi, ws[WS_WW + j]);
    float d  = __fsub_rn(t1, __fmul_rn(2.f, acc));
    sum += d; sq = fmaf(d, d, sq);
    if (d < m1) { m2 = m1; m1 = d; } else if (d < m2) m2 = d;
  }
  r1[t] = m1; r2[t] = m2; rs[t] = sum; rq[t] = sq;
  __syncthreads();
  for (int s = 64; s > 0; s >>= 1) {
    if (t < s) {
      float a1 = r1[t], a2 = r2[t], b1 = r1[t + s], b2 = r2[t + s];
      r1[t] = fminf(a1, b1);
      r2[t] = fminf(fmaxf(a1, b1), fminf(a2, b2));
      rs[t] += rs[t + s]; rq[t] += rq[t + s];
    }
    __syncthreads();
  }
  if (t == 0) {
    ws[WS_MIN2 + i] = r2[0];
    float S = rs[0], Q = rq[0];
    ws[WS_VAR + i] = (Q - S * S / (float)NE) / (float)(NE - 1);
  }
}

// =====================================================================
// k_qmfma: bf16-split MFMA argmin with exactness margin.
// Block 256 thr = 4 waves; block = 128 rows; wave = 32 rows (2 rowtiles).
// 8 phases x 128 codes staged in LDS (64KB, 2 blocks/CU); per ct-tile:
// D[row][code] via 3 mfma chains (hh, hl, lh) x 4 K-slices.
// Per-lane (min1,min2,idx1) tracking; 16-lane lex shuffle reduce;
// margin-pass rows committed, others flagged for exact fp32 fallback.
// =====================================================================
__global__ __launch_bounds__(256, 2) void k_qmfma(const float* __restrict__ z,
                                                  float* __restrict__ wsf,
                                                  float* __restrict__ out) {
  __shared__ unsigned short Lwh[16384];  // 32KB: 128 codes x 128 k (swizzled)
  __shared__ unsigned short Lwl[16384];  // 32KB
  __shared__ float Lww[128];
  const int t    = threadIdx.x;
  const int lane = t & 63;
  const int wq   = t >> 6;       // wave id 0..3
  const int n    = lane & 15;    // col / row-in-tile index
  const int q    = lane >> 4;    // quad 0..3
  const int rowb = blockIdx.x * 128 + wq * 32;

  // ---- A-frags: z rows as bf16 hi/lo (2 rowtiles x 4 K-slices) ----
  s16x8 AH[2][4], AL[2][4];
#pragma unroll
  for (int rt = 0; rt < 2; ++rt) {
    const float* zr = z + (size_t)(rowb + rt * 16 + n) * D;
#pragma unroll
    for (int ks = 0; ks < 4; ++ks) {
      float4 f0 = *(const float4*)(zr + ks * 32 + q * 8);
      float4 f1 = *(const float4*)(zr + ks * 32 + q * 8 + 4);
      float ff[8] = {f0.x, f0.y, f0.z, f0.w, f1.x, f1.y, f1.z, f1.w};
      s16x8 h, l;
#pragma unroll
      for (int j = 0; j < 8; ++j) {
        unsigned short hb = f2bf(ff[j]);
        h[j] = (short)hb;
        l[j] = (short)f2bf(ff[j] - bf2f(hb));
      }
      AH[rt][ks] = h; AL[rt][ks] = l;
    }
  }

  float m1[2][4], m2[2][4]; int i1[2][4];
#pragma unroll
  for (int rt = 0; rt < 2; ++rt)
#pragma unroll
    for (int r = 0; r < 4; ++r) { m1[rt][r] = INFINITY; m2[rt][r] = INFINITY; i1[rt][r] = 0; }

  const unsigned short* whg = (const unsigned short*)(out + SCR);
  const unsigned short* wlg = (const unsigned short*)(out + SCR_WL);

  for (int p = 0; p < 8; ++p) {
    __syncthreads();
    // stage 128 codes of wh/wl (32KB each), linear copy (swizzle preserved)
#pragma unroll
    for (int it = 0; it < 8; ++it) {
      int idx = it * 256 + t;     // 2048 x 16B chunks
      *(s16x8*)&Lwh[idx * 8] = *(const s16x8*)&whg[p * 16384 + idx * 8];
      *(s16x8*)&Lwl[idx * 8] = *(const s16x8*)&wlg[p * 16384 + idx * 8];
    }
    if (t < 128) Lww[t] = wsf[WS_WW + p * 128 + t];
    __syncthreads();

    for (int ct = 0; ct < 8; ++ct) {
      const int cL = ct * 16 + n;          // phase-local code of this lane
      const int c  = p * 128 + cL;         // global code
      s16x8 BH[4], BL[4];
#pragma unroll
      for (int ks = 0; ks < 4; ++ks) {
        unsigned int off = (unsigned int)(cL * 256) +
                           (((unsigned int)(64 * ks + 16 * q)) ^ ((unsigned int)(cL & 7) << 4));
        BH[ks] = *(const s16x8*)&Lwh[off >> 1];
        BL[ks] = *(const s16x8*)&Lwl[off >> 1];
      }
      const float wwc = Lww[cL];
#pragma unroll
      for (int rt = 0; rt < 2; ++rt) {
        f32x4 aA = {0.f, 0.f, 0.f, 0.f};
        f32x4 aB = {0.f, 0.f, 0.f, 0.f};
        f32x4 aC = {0.f, 0.f, 0.f, 0.f};
#pragma unroll
        for (int ks = 0; ks < 4; ++ks) {
          aA = __builtin_amdgcn_mfma_f32_16x16x32_bf16(AH[rt][ks], BH[ks], aA, 0, 0, 0);
          aB = __builtin_amdgcn_mfma_f32_16x16x32_bf16(AH[rt][ks], BL[ks], aB, 0, 0, 0);
          aC = __builtin_amdgcn_mfma_f32_16x16x32_bf16(AL[rt][ks], BH[ks], aC, 0, 0, 0);
        }
#pragma unroll
        for (int r = 0; r < 4; ++r) {
          float dot = (aA[r] + aB[r]) + aC[r];
          float v = fmaf(-2.f, dot, wwc);   // s = ww - 2*dot (zz const per row)
          if (v < m1[rt][r]) { m2[rt][r] = m1[rt][r]; m1[rt][r] = v; i1[rt][r] = c; }
          else m2[rt][r] = fminf(m2[rt][r], v);
        }
      }
    }
  }

  // ---- reduce (m1,m2,i1) across the 16 lanes holding each row ----
  int* rflag = (int*)(out + SCR_RF);
#pragma unroll
  for (int rt = 0; rt < 2; ++rt)
#pragma unroll
    for (int r = 0; r < 4; ++r) {
      float a1 = m1[rt][r], a2 = m2[rt][r]; int ai = i1[rt][r];
#pragma unroll
      for (int mask = 1; mask < 16; mask <<= 1) {
        float b1 = __shfl_xor(a1, mask, 64);
        float b2 = __shfl_xor(a2, mask, 64);
        int   bi = __shfl_xor(ai, mask, 64);
        a2 = fminf(fminf(a2, b2), fmaxf(a1, b1));
        bool take = (b1 < a1) || (b1 == a1 && bi < ai);
        a1 = take ? b1 : a1; ai = take ? bi : ai;
      }
      if (n == 0) {
        int grow = rowb + rt * 16 + q * 4 + r;   // D row = (lane>>4)*4 + reg
        if (a2 - a1 > MARGIN) {
          ((int*)wsf)[WS_IDX + grow] = ai;
          out[OUT_IDX + grow] = (float)ai;
          out[OUT_SI  + grow] = (float)ai;
          ((int*)wsf)[WS_FLAGS + ai] = 1;
        } else {
          rflag[grow] = 1;                        // exact fp32 fallback
        }
      }
    }
}

// ---- exact fp32 fallback for margin-failed rows (R1 numerics) ----
__global__ __launch_bounds__(256) void k_fallback(const float* __restrict__ z,
                                                  const float* __restrict__ w,
                                                  float* __restrict__ wsf,
                                                  float* __restrict__ out) {
  const int t = threadIdx.x;
  const int* rflag = (const int*)(out + SCR_RF);
  __shared__ float zrow[128];
  __shared__ float zzs;
  __shared__ float rv[256];
  __shared__ int   ri[256];
  for (int rr = 0; rr < 128; ++rr) {
    int row = blockIdx.x * 128 + rr;
    if (rflag[row] == 0) continue;      // block-uniform branch
    __syncthreads();
    if (t < 32) ((float4*)zrow)[t] = ((const float4*)(z + (size_t)row * D))[t];
    __syncthreads();
    if (t == 0) zzs = npsq_sum128(zrow);
    __syncthreads();
    float zz = zzs;
    float bv = INFINITY; int bi = 0;
    for (int cc = 0; cc < 4; ++cc) {
      int c = cc * 256 + t;             // ascending per thread
      const float4* wp = (const float4*)(w + (size_t)c * D);
      float acc = 0.f;
#pragma unroll
      for (int k4 = 0; k4 < 32; ++k4) {
        float4 a = wp[k4];
        acc = fmaf(zrow[4*k4+0], a.x, acc); acc = fmaf(zrow[4*k4+1], a.y, acc);
        acc = fmaf(zrow[4*k4+2], a.z, acc); acc = fmaf(zrow[4*k4+3], a.w, acc);
      }
      float d = __fsub_rn(__fadd_rn(zz, wsf[WS_WW + c]), __fmul_rn(2.f, acc));
      if (d < bv) { bv = d; bi = c; }
    }
    rv[t] = bv; ri[t] = bi;
    __syncthreads();
    for (int s = 128; s > 0; s >>= 1) {
      if (t < s) {
        float v2 = rv[t + s]; int i2 = ri[t + s];
        if (v2 < rv[t] || (v2 == rv[t] && i2 < ri[t])) { rv[t] = v2; ri[t] = i2; }
      }
      __syncthreads();
    }
    if (t == 0) {
      int mi = ri[0];
      ((int*)wsf)[WS_IDX + row] = mi;
      out[OUT_IDX + row] = (float)mi;
      out[OUT_SI  + row] = (float)mi;
      ((int*)wsf)[WS_FLAGS + mi] = 1;
    }
  }
}

// ---- gather z_q -> out0, loss partials, per-column square partials ----
__global__ __launch_bounds__(256) void k_gather(const float* __restrict__ z,
                                                const float* __restrict__ w,
                                                float* __restrict__ ws,
                                                float* __restrict__ out) {
  __shared__ float csp[32][8][4];
  __shared__ float lred[256];
  const int t = threadIdx.x, blk = blockIdx.x;
  const int c4 = t & 31, rg = t >> 5;
  float lp = 0.f;
  float csx = 0.f, csy = 0.f, csz = 0.f, csw = 0.f;
  for (int m = 0; m < 16; ++m) {
    int r  = rg + 8 * m;
    int gr = blk * 128 + r;
    int idx = ((const int*)ws)[WS_IDX + gr];
    float4 qv = *(const float4*)&w[idx * D + c4 * 4];
    float4 zv = *(const float4*)&z[(size_t)gr * D + c4 * 4];
    *(float4*)&out[OUT_ZQ + (size_t)gr * D + c4 * 4] = qv;
    float dx = qv.x - zv.x, dy = qv.y - zv.y, dz = qv.z - zv.z, dw = qv.w - zv.w;
    lp = fmaf(dx, dx, lp); lp = fmaf(dy, dy, lp);
    lp = fmaf(dz, dz, lp); lp = fmaf(dw, dw, lp);
    csx = fmaf(qv.x, qv.x, csx); csy = fmaf(qv.y, qv.y, csy);
    csz = fmaf(qv.z, qv.z, csz); csw = fmaf(qv.w, qv.w, csw);
  }
  csp[c4][rg][0] = csx; csp[c4][rg][1] = csy;
  csp[c4][rg][2] = csz; csp[c4][rg][3] = csw;
  lred[t] = lp;
  __syncthreads();
  for (int s = 128; s > 0; s >>= 1) {
    if (t < s) lred[t] += lred[t + s];
    __syncthreads();
  }
  if (t == 0) ws[WS_LOSSP + blk] = lred[0];
  if (t < 128) {
    int dcol = t;
    float s = 0.f;
    for (int g = 0; g < 8; ++g) s += csp[dcol >> 2][g][dcol & 3];
    ws[WS_COLSQP + blk * 128 + dcol] = s;
  }
}

// ---- combine colsq partials ----
__global__ __launch_bounds__(256) void k_colsq_final(float* __restrict__ ws) {
  int t = blockIdx.x * 256 + threadIdx.x;
  if (t >= NB * D) return;
  int b = t >> 7, dcol = t & 127;
  float s = 0.f;
  for (int rb = 0; rb < 32; ++rb)
    s += ws[WS_COLSQP + (b * 32 + rb) * 128 + dcol];
  ws[WS_COLSQ + t] = s;
}

// ---- zn = z_q / max(||z_q[b,:,d]||, 1e-12)  (normalize over N axis) ----
__global__ __launch_bounds__(256) void k_zn(const float* __restrict__ ws,
                                            float* __restrict__ out) {
  int u = blockIdx.x * 256 + threadIdx.x;
  const int total4 = NROWS * D / 4;
  for (; u < total4; u += gridDim.x * 256) {
    float4 qv = ((const float4*)out)[u];
    int o = u * 4;
    int b = o >> 19;
    int dcol = o & 127;
    float4 cs = *(const float4*)&ws[WS_COLSQ + b * 128 + dcol];
    out[OUT_ZN + o + 0] = qv.x / fmaxf(sqrtf(cs.x), 1e-12f);
    out[OUT_ZN + o + 1] = qv.y / fmaxf(sqrtf(cs.y), 1e-12f);
    out[OUT_ZN + o + 2] = qv.z / fmaxf(sqrtf(cs.z), 1e-12f);
    out[OUT_ZN + o + 3] = qv.w / fmaxf(sqrtf(cs.w), 1e-12f);
  }
}

// ---- finalize scalars + sampled_idx ----
__global__ __launch_bounds__(1024) void k_final(float* __restrict__ ws,
                                                float* __restrict__ out) {
  __shared__ float s1[1024], s2[1024], s3[1024];
  int t = threadIdx.x;
  s1[t] = (t < 512) ? ws[WS_LOSSP + t] : 0.f;
  s2[t] = ws[WS_MIN2 + t];
  s3[t] = ws[WS_VAR + t];
  __syncthreads();
  for (int s = 512; s > 0; s >>= 1) {
    if (t < s) { s1[t] += s1[t + s]; s2[t] += s2[t + s]; s3[t] += s3[t + s]; }
    __syncthreads();
  }
  if (t == 0) {
    float m = s1[0] / 8388608.f;
    out[OUT_LOSS] = m + 0.9f * m;
    out[OUT_VAR]  = s3[0] / 1024.f;
    out[OUT_DIST] = s2[0] / 1024.f;
  }
  const int* flags = (const int*)ws + WS_FLAGS;
  for (int i = t; i < NB * NE; i += 1024)
    out[OUT_SAMP + i] = (i < NE && flags[i] != 0) ? 1.f : 0.f;
}

extern "C" void kernel_launch(void* const* d_in, const int* in_sizes, int n_in,
                              void* d_out, int out_size, void* d_ws, size_t ws_size,
                              hipStream_t stream) {
  const float* z = (const float*)d_in[0];
  const float* w = (const float*)d_in[1];
  float* out = (float*)d_out;
  float* ws  = (float*)d_ws;

  hipMemsetAsync((char*)d_ws + (size_t)WS_FLAGS * 4, 0, NE * 4, stream);
  hipMemsetAsync((char*)d_out + (size_t)SCR_RF * 4, 0, NROWS * 4, stream);
  hipLaunchKernelGGL(k_wsplit,      dim3(1024), dim3(128),  0, stream, w, out);
  hipLaunchKernelGGL(k_ww,          dim3(8),    dim3(128),  0, stream, w, ws);
  hipLaunchKernelGGL(k_cb,          dim3(1024), dim3(128),  0, stream, w, ws);
  hipLaunchKernelGGL(k_qmfma,       dim3(512),  dim3(256),  0, stream, z, ws, out);
  hipLaunchKernelGGL(k_fallback,    dim3(512),  dim3(256),  0, stream, z, w, ws, out);
  hipLaunchKernelGGL(k_gather,      dim3(512),  dim3(256),  0, stream, z, w, ws, out);
  hipLaunchKernelGGL(k_colsq_final, dim3(8),    dim3(256),  0, stream, ws);
  hipLaunchKernelGGL(k_zn,          dim3(2048), dim3(256),  0, stream, ws, out);
  hipLaunchKernelGGL(k_final,       dim3(1),    dim3(1024), 0, stream, ws, out);
}

// Round 5
// 180.045 us; speedup vs baseline: 5.8837x; 1.2955x over previous
//
#include <hip/hip_runtime.h>
#include <math.h>

// Problem constants (z: [16,4096,128] f32, emb_w: [1024,128] f32, unit rows)
#define D       128
#define NE      1024
#define NROWS   65536   // B*N
#define NB      16

// ---- output float offsets (total 16,924,675 floats) ----
#define OUT_ZQ    0            // [16,4096,128]
#define OUT_LOSS  8388608      // scalar
#define OUT_SAMP  8388609      // [16,1024]
#define OUT_IDX   8404993      // [16,4096] (float)
#define OUT_VAR   8470529      // scalar
#define OUT_DIST  8470530      // scalar
#define OUT_SI    8470531      // [16,4096] (float)
#define OUT_ZN    8536067      // [16,4096,128]  (overwritten LAST by k_zn)

// Scratch inside the OUT_ZN region (k_zn overwrites it at the very end).
// SCR is 16B-aligned (8536068*4 % 16 == 0).
#define SCR       8536068         // wh: 131072 ushorts (256KB)
#define SCR_WL    (SCR + 65536)   // wl: 131072 ushorts (256KB)
#define SCR_CNT   (SCR + 131072)  // int counter (zeroed per call)
#define SCR_LIST  (SCR + 131073)  // int[<=65536] flagged-row list

// ---- workspace float offsets (538 KB total) ----
#define WS_IDX    0            // int[65536]
#define WS_WW     65536        // float[1024]
#define WS_FLAGS  66560        // int[1024]
#define WS_MIN2   67584        // float[1024]
#define WS_VAR    68608        // float[1024]
#define WS_LOSSP  69632        // float[512]
#define WS_COLSQP 70144        // float[512*128]
#define WS_COLSQ  135680       // float[16*128]

#define MARGIN 2e-3f

typedef __attribute__((ext_vector_type(8))) short s16x8;   // 8 bf16 (4 VGPR)
typedef __attribute__((ext_vector_type(4))) float f32x4;

__device__ __forceinline__ unsigned short f2bf(float f) {  // bf16 RNE
  unsigned int u = __float_as_uint(f);
  return (unsigned short)((u + 0x7FFFu + ((u >> 16) & 1u)) >> 16);
}
__device__ __forceinline__ float bf2f(unsigned short h) {
  return __uint_as_float(((unsigned int)h) << 16);
}

// numpy pairwise sum of squares over 128 contiguous floats (exact ref order).
__device__ __forceinline__ float npsq_sum128(const float* p) {
  float a[8];
#pragma unroll
  for (int m = 0; m < 8; ++m) a[m] = __fmul_rn(p[m], p[m]);
  for (int k = 8; k < 128; k += 8) {
#pragma unroll
    for (int m = 0; m < 8; ++m) a[m] = __fadd_rn(a[m], __fmul_rn(p[k + m], p[k + m]));
  }
  float s01 = __fadd_rn(a[0], a[1]);
  float s23 = __fadd_rn(a[2], a[3]);
  float s45 = __fadd_rn(a[4], a[5]);
  float s67 = __fadd_rn(a[6], a[7]);
  return __fadd_rn(__fadd_rn(s01, s23), __fadd_rn(s45, s67));
}

// ---- ww[c] = sum(w[c]^2), numpy order ----
__global__ __launch_bounds__(128) void k_ww(const float* __restrict__ w,
                                            float* __restrict__ ws) {
  int c = blockIdx.x * 128 + threadIdx.x;
  if (c >= NE) return;
  ws[WS_WW + c] = npsq_sum128(w + c * D);
}

// ---- split w into bf16 hi/lo, stored XOR-swizzled in the OUT scratch ----
// byte(c,k) = (c*256 + 2k) ^ ((c&7)<<4); XOR touches only byte-addr bits 4-6
// so 16B chunks map to 16B chunks -> one s16x8 store per thread.
__global__ __launch_bounds__(256) void k_wsplit(const float* __restrict__ w,
                                                float* __restrict__ out) {
  int u = blockIdx.x * 256 + threadIdx.x;   // 16384 = 1024 codes x 16 octets
  int c = u >> 4, j = u & 15;
  const float4* p = (const float4*)(w + c * D + j * 8);
  float4 f0 = p[0], f1 = p[1];
  float ff[8] = {f0.x, f0.y, f0.z, f0.w, f1.x, f1.y, f1.z, f1.w};
  s16x8 h, l;
#pragma unroll
  for (int e = 0; e < 8; ++e) {
    unsigned short hb = f2bf(ff[e]);
    h[e] = (short)hb;
    l[e] = (short)f2bf(ff[e] - bf2f(hb));
  }
  unsigned int by = ((unsigned int)(c * 256 + j * 16)) ^ ((unsigned int)((c & 7) << 4));
  *(s16x8*)((char*)(out + SCR) + by)    = h;
  *(s16x8*)((char*)(out + SCR_WL) + by) = l;
}

// ---- codebook self-distance stats ----
__global__ __launch_bounds__(128) void k_cb(const float* __restrict__ w,
                                            float* __restrict__ ws) {
  const int i = blockIdx.x;
  const int t = threadIdx.x;
  __shared__ float4 wi[32];
  __shared__ float r1[128], r2[128], rs[128], rq[128];
  if (t < 32) wi[t] = ((const float4*)(w + i * D))[t];
  __syncthreads();
  const float wwi = ws[WS_WW + i];
  float m1 = INFINITY, m2 = INFINITY, sum = 0.f, sq = 0.f;
  for (int jj = 0; jj < 8; ++jj) {
    int j = t + jj * 128;
    const float4* pj = (const float4*)(w + j * D);
    float acc = 0.f;
#pragma unroll
    for (int k4 = 0; k4 < 32; ++k4) {
      float4 a = wi[k4], b = pj[k4];
      acc = fmaf(a.x, b.x, acc); acc = fmaf(a.y, b.y, acc);
      acc = fmaf(a.z, b.z, acc); acc = fmaf(a.w, b.w, acc);
    }
    float t1 = __fadd_rn(wwi, ws[WS_WW + j]);
    float d  = __fsub_rn(t1, __fmul_rn(2.f, acc));
    sum += d; sq = fmaf(d, d, sq);
    if (d < m1) { m2 = m1; m1 = d; } else if (d < m2) m2 = d;
  }
  r1[t] = m1; r2[t] = m2; rs[t] = sum; rq[t] = sq;
  __syncthreads();
  for (int s = 64; s > 0; s >>= 1) {
    if (t < s) {
      float a1 = r1[t], a2 = r2[t], b1 = r1[t + s], b2 = r2[t + s];
      r1[t] = fminf(a1, b1);
      r2[t] = fminf(fmaxf(a1, b1), fminf(a2, b2));
      rs[t] += rs[t + s]; rq[t] += rq[t + s];
    }
    __syncthreads();
  }
  if (t == 0) {
    ws[WS_MIN2 + i] = r2[0];
    float S = rs[0], Q = rq[0];
    ws[WS_VAR + i] = (Q - S * S / (float)NE) / (float)(NE - 1);
  }
}

// =====================================================================
// k_qmfma: bf16-split MFMA argmin with exactness margin.
// Margin-failed rows are APPENDED to a compact list (atomicAdd) instead
// of a per-row flag array -> fallback does zero skip-scanning.
// =====================================================================
__global__ __launch_bounds__(256, 2) void k_qmfma(const float* __restrict__ z,
                                                  float* __restrict__ wsf,
                                                  float* __restrict__ out) {
  __shared__ unsigned short Lwh[16384];  // 32KB: 128 codes x 128 k (swizzled)
  __shared__ unsigned short Lwl[16384];  // 32KB
  __shared__ float Lww[128];
  const int t    = threadIdx.x;
  const int lane = t & 63;
  const int wq   = t >> 6;       // wave id 0..3
  const int n    = lane & 15;    // col / row-in-tile index
  const int q    = lane >> 4;    // quad 0..3
  const int rowb = blockIdx.x * 128 + wq * 32;

  // ---- A-frags: z rows as bf16 hi/lo (2 rowtiles x 4 K-slices) ----
  s16x8 AH[2][4], AL[2][4];
#pragma unroll
  for (int rt = 0; rt < 2; ++rt) {
    const float* zr = z + (size_t)(rowb + rt * 16 + n) * D;
#pragma unroll
    for (int ks = 0; ks < 4; ++ks) {
      float4 f0 = *(const float4*)(zr + ks * 32 + q * 8);
      float4 f1 = *(const float4*)(zr + ks * 32 + q * 8 + 4);
      float ff[8] = {f0.x, f0.y, f0.z, f0.w, f1.x, f1.y, f1.z, f1.w};
      s16x8 h, l;
#pragma unroll
      for (int j = 0; j < 8; ++j) {
        unsigned short hb = f2bf(ff[j]);
        h[j] = (short)hb;
        l[j] = (short)f2bf(ff[j] - bf2f(hb));
      }
      AH[rt][ks] = h; AL[rt][ks] = l;
    }
  }

  float m1[2][4], m2[2][4]; int i1[2][4];
#pragma unroll
  for (int rt = 0; rt < 2; ++rt)
#pragma unroll
    for (int r = 0; r < 4; ++r) { m1[rt][r] = INFINITY; m2[rt][r] = INFINITY; i1[rt][r] = 0; }

  const unsigned short* whg = (const unsigned short*)(out + SCR);
  const unsigned short* wlg = (const unsigned short*)(out + SCR_WL);

  for (int p = 0; p < 8; ++p) {
    __syncthreads();
#pragma unroll
    for (int it = 0; it < 8; ++it) {
      int idx = it * 256 + t;     // 2048 x 16B chunks
      *(s16x8*)&Lwh[idx * 8] = *(const s16x8*)&whg[p * 16384 + idx * 8];
      *(s16x8*)&Lwl[idx * 8] = *(const s16x8*)&wlg[p * 16384 + idx * 8];
    }
    if (t < 128) Lww[t] = wsf[WS_WW + p * 128 + t];
    __syncthreads();

    for (int ct = 0; ct < 8; ++ct) {
      const int cL = ct * 16 + n;          // phase-local code of this lane
      const int c  = p * 128 + cL;         // global code
      s16x8 BH[4], BL[4];
#pragma unroll
      for (int ks = 0; ks < 4; ++ks) {
        unsigned int off = (unsigned int)(cL * 256) +
                           (((unsigned int)(64 * ks + 16 * q)) ^ ((unsigned int)(cL & 7) << 4));
        BH[ks] = *(const s16x8*)&Lwh[off >> 1];
        BL[ks] = *(const s16x8*)&Lwl[off >> 1];
      }
      const float wwc = Lww[cL];
#pragma unroll
      for (int rt = 0; rt < 2; ++rt) {
        f32x4 aA = {0.f, 0.f, 0.f, 0.f};
        f32x4 aB = {0.f, 0.f, 0.f, 0.f};
        f32x4 aC = {0.f, 0.f, 0.f, 0.f};
#pragma unroll
        for (int ks = 0; ks < 4; ++ks) {
          aA = __builtin_amdgcn_mfma_f32_16x16x32_bf16(AH[rt][ks], BH[ks], aA, 0, 0, 0);
          aB = __builtin_amdgcn_mfma_f32_16x16x32_bf16(AH[rt][ks], BL[ks], aB, 0, 0, 0);
          aC = __builtin_amdgcn_mfma_f32_16x16x32_bf16(AL[rt][ks], BH[ks], aC, 0, 0, 0);
        }
#pragma unroll
        for (int r = 0; r < 4; ++r) {
          float dot = (aA[r] + aB[r]) + aC[r];
          float v = fmaf(-2.f, dot, wwc);   // s = ww - 2*dot (zz const per row)
          if (v < m1[rt][r]) { m2[rt][r] = m1[rt][r]; m1[rt][r] = v; i1[rt][r] = c; }
          else m2[rt][r] = fminf(m2[rt][r], v);
        }
      }
    }
  }

  // ---- reduce (m1,m2,i1) across the 16 lanes holding each row ----
#pragma unroll
  for (int rt = 0; rt < 2; ++rt)
#pragma unroll
    for (int r = 0; r < 4; ++r) {
      float a1 = m1[rt][r], a2 = m2[rt][r]; int ai = i1[rt][r];
#pragma unroll
      for (int mask = 1; mask < 16; mask <<= 1) {
        float b1 = __shfl_xor(a1, mask, 64);
        float b2 = __shfl_xor(a2, mask, 64);
        int   bi = __shfl_xor(ai, mask, 64);
        a2 = fminf(fminf(a2, b2), fmaxf(a1, b1));
        bool take = (b1 < a1) || (b1 == a1 && bi < ai);
        a1 = take ? b1 : a1; ai = take ? bi : ai;
      }
      if (n == 0) {
        int grow = rowb + rt * 16 + q * 4 + r;   // D row = (lane>>4)*4 + reg
        if (a2 - a1 > MARGIN) {
          ((int*)wsf)[WS_IDX + grow] = ai;
          out[OUT_IDX + grow] = (float)ai;
          out[OUT_SI  + grow] = (float)ai;
          ((int*)wsf)[WS_FLAGS + ai] = 1;
        } else {
          int pos = atomicAdd(((int*)out) + SCR_CNT, 1);
          ((int*)out)[SCR_LIST + pos] = grow;    // exact fp32 fallback row
        }
      }
    }
}

// ---- exact fp32 fallback over the compact flagged-row list ----
__global__ __launch_bounds__(256) void k_fallback(const float* __restrict__ z,
                                                  const float* __restrict__ w,
                                                  float* __restrict__ wsf,
                                                  float* __restrict__ out) {
  const int t = threadIdx.x;
  const int count = ((const int*)out)[SCR_CNT];
  const int* list = ((const int*)out) + SCR_LIST;
  __shared__ float zrow[128];
  __shared__ float zzs;
  __shared__ float rv[256];
  __shared__ int   ri[256];
  for (int i = blockIdx.x; i < count; i += gridDim.x) {
    int row = list[i];
    __syncthreads();   // protect zrow reuse across iterations
    if (t < 32) ((float4*)zrow)[t] = ((const float4*)(z + (size_t)row * D))[t];
    __syncthreads();
    if (t == 0) zzs = npsq_sum128(zrow);
    __syncthreads();
    float zz = zzs;
    float bv = INFINITY; int bi = 0;
    for (int cc = 0; cc < 4; ++cc) {
      int c = cc * 256 + t;             // ascending per thread
      const float4* wp = (const float4*)(w + (size_t)c * D);
      float acc = 0.f;
#pragma unroll
      for (int k4 = 0; k4 < 32; ++k4) {
        float4 a = wp[k4];
        acc = fmaf(zrow[4*k4+0], a.x, acc); acc = fmaf(zrow[4*k4+1], a.y, acc);
        acc = fmaf(zrow[4*k4+2], a.z, acc); acc = fmaf(zrow[4*k4+3], a.w, acc);
      }
      float d = __fsub_rn(__fadd_rn(zz, wsf[WS_WW + c]), __fmul_rn(2.f, acc));
      if (d < bv) { bv = d; bi = c; }
    }
    rv[t] = bv; ri[t] = bi;
    __syncthreads();
    for (int s = 128; s > 0; s >>= 1) {
      if (t < s) {
        float v2 = rv[t + s]; int i2 = ri[t + s];
        if (v2 < rv[t] || (v2 == rv[t] && i2 < ri[t])) { rv[t] = v2; ri[t] = i2; }
      }
      __syncthreads();
    }
    if (t == 0) {
      int mi = ri[0];
      ((int*)wsf)[WS_IDX + row] = mi;
      out[OUT_IDX + row] = (float)mi;
      out[OUT_SI  + row] = (float)mi;
      ((int*)wsf)[WS_FLAGS + mi] = 1;
    }
  }
}

// ---- gather z_q -> out0, loss partials, per-column square partials ----
__global__ __launch_bounds__(256) void k_gather(const float* __restrict__ z,
                                                const float* __restrict__ w,
                                                float* __restrict__ ws,
                                                float* __restrict__ out) {
  __shared__ float csp[32][8][4];
  __shared__ float lred[256];
  const int t = threadIdx.x, blk = blockIdx.x;
  const int c4 = t & 31, rg = t >> 5;
  float lp = 0.f;
  float csx = 0.f, csy = 0.f, csz = 0.f, csw = 0.f;
  for (int m = 0; m < 16; ++m) {
    int r  = rg + 8 * m;
    int gr = blk * 128 + r;
    int idx = ((const int*)ws)[WS_IDX + gr];
    float4 qv = *(const float4*)&w[idx * D + c4 * 4];
    float4 zv = *(const float4*)&z[(size_t)gr * D + c4 * 4];
    *(float4*)&out[OUT_ZQ + (size_t)gr * D + c4 * 4] = qv;
    float dx = qv.x - zv.x, dy = qv.y - zv.y, dz = qv.z - zv.z, dw = qv.w - zv.w;
    lp = fmaf(dx, dx, lp); lp = fmaf(dy, dy, lp);
    lp = fmaf(dz, dz, lp); lp = fmaf(dw, dw, lp);
    csx = fmaf(qv.x, qv.x, csx); csy = fmaf(qv.y, qv.y, csy);
    csz = fmaf(qv.z, qv.z, csz); csw = fmaf(qv.w, qv.w, csw);
  }
  csp[c4][rg][0] = csx; csp[c4][rg][1] = csy;
  csp[c4][rg][2] = csz; csp[c4][rg][3] = csw;
  lred[t] = lp;
  __syncthreads();
  for (int s = 128; s > 0; s >>= 1) {
    if (t < s) lred[t] += lred[t + s];
    __syncthreads();
  }
  if (t == 0) ws[WS_LOSSP + blk] = lred[0];
  if (t < 128) {
    int dcol = t;
    float s = 0.f;
    for (int g = 0; g < 8; ++g) s += csp[dcol >> 2][g][dcol & 3];
    ws[WS_COLSQP + blk * 128 + dcol] = s;
  }
}

// ---- combine colsq partials ----
__global__ __launch_bounds__(256) void k_colsq_final(float* __restrict__ ws) {
  int t = blockIdx.x * 256 + threadIdx.x;
  if (t >= NB * D) return;
  int b = t >> 7, dcol = t & 127;
  float s = 0.f;
  for (int rb = 0; rb < 32; ++rb)
    s += ws[WS_COLSQP + (b * 32 + rb) * 128 + dcol];
  ws[WS_COLSQ + t] = s;
}

// ---- zn = z_q / max(||z_q[b,:,d]||, 1e-12)  (normalize over N axis) ----
__global__ __launch_bounds__(256) void k_zn(const float* __restrict__ ws,
                                            float* __restrict__ out) {
  int u = blockIdx.x * 256 + threadIdx.x;
  const int total4 = NROWS * D / 4;
  for (; u < total4; u += gridDim.x * 256) {
    float4 qv = ((const float4*)out)[u];
    int o = u * 4;
    int b = o >> 19;
    int dcol = o & 127;
    float4 cs = *(const float4*)&ws[WS_COLSQ + b * 128 + dcol];
    out[OUT_ZN + o + 0] = qv.x / fmaxf(sqrtf(cs.x), 1e-12f);
    out[OUT_ZN + o + 1] = qv.y / fmaxf(sqrtf(cs.y), 1e-12f);
    out[OUT_ZN + o + 2] = qv.z / fmaxf(sqrtf(cs.z), 1e-12f);
    out[OUT_ZN + o + 3] = qv.w / fmaxf(sqrtf(cs.w), 1e-12f);
  }
}

// ---- finalize scalars + sampled_idx ----
__global__ __launch_bounds__(1024) void k_final(float* __restrict__ ws,
                                                float* __restrict__ out) {
  __shared__ float s1[1024], s2[1024], s3[1024];
  int t = threadIdx.x;
  s1[t] = (t < 512) ? ws[WS_LOSSP + t] : 0.f;
  s2[t] = ws[WS_MIN2 + t];
  s3[t] = ws[WS_VAR + t];
  __syncthreads();
  for (int s = 512; s > 0; s >>= 1) {
    if (t < s) { s1[t] += s1[t + s]; s2[t] += s2[t + s]; s3[t] += s3[t + s]; }
    __syncthreads();
  }
  if (t == 0) {
    float m = s1[0] / 8388608.f;
    out[OUT_LOSS] = m + 0.9f * m;
    out[OUT_VAR]  = s3[0] / 1024.f;
    out[OUT_DIST] = s2[0] / 1024.f;
  }
  const int* flags = (const int*)ws + WS_FLAGS;
  for (int i = t; i < NB * NE; i += 1024)
    out[OUT_SAMP + i] = (i < NE && flags[i] != 0) ? 1.f : 0.f;
}

extern "C" void kernel_launch(void* const* d_in, const int* in_sizes, int n_in,
                              void* d_out, int out_size, void* d_ws, size_t ws_size,
                              hipStream_t stream) {
  const float* z = (const float*)d_in[0];
  const float* w = (const float*)d_in[1];
  float* out = (float*)d_out;
  float* ws  = (float*)d_ws;

  hipMemsetAsync((char*)d_ws + (size_t)WS_FLAGS * 4, 0, NE * 4, stream);
  hipMemsetAsync((char*)d_out + (size_t)SCR_CNT * 4, 0, 4, stream);
  hipLaunchKernelGGL(k_wsplit,      dim3(64),   dim3(256),  0, stream, w, out);
  hipLaunchKernelGGL(k_ww,          dim3(8),    dim3(128),  0, stream, w, ws);
  hipLaunchKernelGGL(k_cb,          dim3(1024), dim3(128),  0, stream, w, ws);
  hipLaunchKernelGGL(k_qmfma,       dim3(512),  dim3(256),  0, stream, z, ws, out);
  hipLaunchKernelGGL(k_fallback,    dim3(1024), dim3(256),  0, stream, z, w, ws, out);
  hipLaunchKernelGGL(k_gather,      dim3(512),  dim3(256),  0, stream, z, w, ws, out);
  hipLaunchKernelGGL(k_colsq_final, dim3(8),    dim3(256),  0, stream, ws);
  hipLaunchKernelGGL(k_zn,          dim3(2048), dim3(256),  0, stream, ws, out);
  hipLaunchKernelGGL(k_final,       dim3(1),    dim3(1024), 0, stream, ws, out);
}